// Round 7
// baseline (118.026 us; speedup 1.0000x reference)
//
#include <hip/hip_runtime.h>

// VQ argmin via MFMA: x [16,64,64,64] NCHW fp32, codebook [1024,64] fp32.
// dist = ||e||^2 + (-2x).e  (||x||^2 dropped).  -2x.e computed as bf16 3-way
// split GEMM (h/m/l, keep level-sum<=2 products: hh,hm,mh,hl,mm,lh) -> exact
// to ~2^-26, below fp32 rounding noise.
//
// R15: R8-R14 (6 schedules: LDS-shared-B with every barrier discipline) all
// cap at MfmaUtil 33-37%.  Accounting shows MfmaUtil == matrix-demand/wall
// in every one: the pipes run SERIALLY because LDS-shared-B forces barrier
// lockstep (8 waves/CU all in the same region type; our MFMA:LDS ratio ~1.3
// can't amortize it, unlike m201's ~10).  Fix: NO LDS for B, NO barriers.
// Each wave double-buffers its 12 B-frags in REGISTERS straight from global
// (codebook = 384KB, L1/L2-resident; 12x global_load_dwordx4 per tile,
// coalesced 1KB/inst, compiler-counted vmcnt).  The SIMD's 2 waves free-run
// into antiphase and cover each other's VALU/load time -- the overlap that
// lockstep forbade.  VGPR ~210 (A 48 + B-dbuf 96 + acc 32 + argmin 48) at
// 2 waves/SIMD.  Numerics identical to R13/R14 (absmax 0).

typedef float f4 __attribute__((ext_vector_type(4)));
typedef float f32x16 __attribute__((ext_vector_type(16)));
typedef short s8v __attribute__((ext_vector_type(8)));
typedef unsigned int u32;

#define D_DIM 64
#define HW    4096
#define ROWSB 128
#define INF_  __builtin_inff()
#define M32(a,b,c) __builtin_amdgcn_mfma_f32_32x32x16_bf16(a,b,c,0,0,0)
#define Z16 (f32x16){0.f,0.f,0.f,0.f,0.f,0.f,0.f,0.f,0.f,0.f,0.f,0.f,0.f,0.f,0.f,0.f}

__device__ __forceinline__ unsigned short bf_rne(float f) {
    u32 u = __builtin_bit_cast(u32, f);
    u32 r = u + 0x7fffu + ((u >> 16) & 1u);
    return (unsigned short)(r >> 16);
}
__device__ __forceinline__ float bf_to_f(unsigned short h) {
    u32 u = ((u32)h) << 16;
    return __builtin_bit_cast(float, u);
}
__device__ __forceinline__ void split3(float f, unsigned short& h,
                                       unsigned short& m, unsigned short& l) {
    h = bf_rne(f);
    float f1 = f - bf_to_f(h);
    m = bf_rne(f1);
    float f2 = f1 - bf_to_f(m);
    l = bf_rne(f2);
}
__device__ __forceinline__ s8v pack8(unsigned short a0, unsigned short a1,
                                     unsigned short a2, unsigned short a3,
                                     unsigned short a4, unsigned short a5,
                                     unsigned short a6, unsigned short a7) {
    uint4 u;
    u.x = a0 | ((u32)a1 << 16);
    u.y = a2 | ((u32)a3 << 16);
    u.z = a4 | ((u32)a5 << 16);
    u.w = a6 | ((u32)a7 << 16);
    return __builtin_bit_cast(s8v, u);
}

// ---- prep: split codebook into 32x32x16 B-fragment-ordered bf16 h/m/l
// chunks + enorm.  Chunk c = T*12 + s*3 + L (T = 32-code tile 0..31,
// s = kstep 0..3, L = level): 64 lanes x 16B.  lane: code = T*32 + (lane&31),
// k = s*16 + (lane>>5)*8 + j  (B[k][n]: n = lane&31, k = (lane>>5)*8 + j).
// enorm (fp32, exact) at ws + 384KB.
__global__ __launch_bounds__(64) void prep_kernel(const float* __restrict__ cb,
                                                  char* __restrict__ wsb) {
    const int blk = blockIdx.x;
    const int lane = threadIdx.x;
    if (blk < 384) {
        const int T = blk / 12;
        const int rem = blk - T * 12;
        const int s = rem / 3;
        const int L = rem - s * 3;
        const int code = T * 32 + (lane & 31);
        const int ch0 = s * 16 + (lane >> 5) * 8;
        const float* src = cb + code * 64 + ch0;
        unsigned short o[8];
#pragma unroll
        for (int j = 0; j < 8; ++j) {
            unsigned short h, m2, l;
            split3(src[j], h, m2, l);
            o[j] = (L == 0) ? h : (L == 1) ? m2 : l;
        }
        uint4 w;
        w.x = o[0] | ((u32)o[1] << 16);
        w.y = o[2] | ((u32)o[3] << 16);
        w.z = o[4] | ((u32)o[5] << 16);
        w.w = o[6] | ((u32)o[7] << 16);
        *(uint4*)(wsb + (size_t)blk * 1024 + lane * 16) = w;
    } else {
        const int k = (blk - 384) * 64 + lane;
        const f4* row = (const f4*)(cb + (size_t)k * 64);
        float sacc = 0.f;
#pragma unroll
        for (int i = 0; i < 16; ++i) {
            f4 v = row[i];
            sacc = fmaf(v.x, v.x, sacc);
            sacc = fmaf(v.y, v.y, sacc);
            sacc = fmaf(v.z, v.z, sacc);
            sacc = fmaf(v.w, v.w, sacc);
        }
        ((float*)(wsb + 384 * 1024))[k] = sacc;
    }
}

// build A-frags of (-2x) for this wave's 32 rows, kstep s (k = s*16 + lh8 + j)
#define BUILD_A(s) { \
    const float* xr = (const float*)&xs4[w32 + l31][0]; \
    f4 va = *(const f4*)(xr + (s) * 16 + lh8); \
    f4 vb = *(const f4*)(xr + (s) * 16 + lh8 + 4); \
    unsigned short h0,h1,h2,h3,h4,h5,h6,h7; \
    unsigned short q0,q1,q2,q3,q4,q5,q6,q7; \
    unsigned short l0,l1,l2,l3,l4,l5,l6,l7; \
    split3(-2.f * va.x, h0, q0, l0); split3(-2.f * va.y, h1, q1, l1); \
    split3(-2.f * va.z, h2, q2, l2); split3(-2.f * va.w, h3, q3, l3); \
    split3(-2.f * vb.x, h4, q4, l4); split3(-2.f * vb.y, h5, q5, l5); \
    split3(-2.f * vb.z, h6, q6, l6); split3(-2.f * vb.w, h7, q7, l7); \
    Ah##s = pack8(h0,h1,h2,h3,h4,h5,h6,h7); \
    Am##s = pack8(q0,q1,q2,q3,q4,q5,q6,q7); \
    Al##s = pack8(l0,l1,l2,l3,l4,l5,l6,l7); \
}

// load all 12 B-frags of one tile (base TB) into reg set SET -- 12 coalesced
// global_load_dwordx4 (1KB/inst); compiler inserts counted vmcnt before use.
#define LDG(SET, TB) { \
    const char* _g = (TB) + lane16; \
    B##SET##0h = *(const s8v*)(_g);          B##SET##0m = *(const s8v*)(_g + 1024); \
    B##SET##0l = *(const s8v*)(_g + 2048);   B##SET##1h = *(const s8v*)(_g + 3072); \
    B##SET##1m = *(const s8v*)(_g + 4096);   B##SET##1l = *(const s8v*)(_g + 5120); \
    B##SET##2h = *(const s8v*)(_g + 6144);   B##SET##2m = *(const s8v*)(_g + 7168); \
    B##SET##2l = *(const s8v*)(_g + 8192);   B##SET##3h = *(const s8v*)(_g + 9216); \
    B##SET##3m = *(const s8v*)(_g + 10240);  B##SET##3l = *(const s8v*)(_g + 11264); \
}

// 6 products of kstep s from reg set SET, alternating the 2 acc chains
#define K6G(s, SET) \
    c0 = M32(Ah##s, B##SET##s##h, c0); c1 = M32(Ah##s, B##SET##s##m, c1); \
    c0 = M32(Am##s, B##SET##s##h, c0); c1 = M32(Ah##s, B##SET##s##l, c1); \
    c0 = M32(Am##s, B##SET##s##m, c0); c1 = M32(Al##s, B##SET##s##h, c1);

#define K24(SET) \
    __builtin_amdgcn_s_setprio(1); \
    K6G(0, SET) K6G(1, SET) K6G(2, SET) K6G(3, SET) \
    __builtin_amdgcn_s_setprio(0);

// pipelined argmin update of the PREVIOUS tile (svp/kprev)
#define UPD(i) { \
    bool pr = (svp[i] < best##i); \
    best##i = pr ? svp[i] : best##i; \
    idx##i  = pr ? kprev : idx##i; \
}
#define UPD_ALL \
    UPD(0)  UPD(1)  UPD(2)  UPD(3)  UPD(4)  UPD(5)  UPD(6)  UPD(7) \
    UPD(8)  UPD(9)  UPD(10) UPD(11) UPD(12) UPD(13) UPD(14) UPD(15)

// finish tile: save distances, reseed chains for tile tn (en uniform over the
// lane's 16 C regs since C col = lane&31 = code)
#define FINISH(kbase, tn) { \
    svp = c0 + c1; \
    kprev = (kbase) + l31; \
    const float _en = sEn[(((tn) & 31) << 5) + l31]; \
    _Pragma("unroll") \
    for (int _i = 0; _i < 16; ++_i) c0[_i] = _en; \
    c1 = Z16; \
}

#define BF1(i, msk) { \
    float ov = __shfl_xor(best##i, msk); \
    int   oi = __shfl_xor(idx##i,  msk); \
    bool pr = (ov < best##i) || (ov == best##i && oi < idx##i); \
    best##i = pr ? ov : best##i; \
    idx##i  = pr ? oi : idx##i; \
}
#define BFALL(msk) \
    BF1(0,msk)  BF1(1,msk)  BF1(2,msk)  BF1(3,msk) \
    BF1(4,msk)  BF1(5,msk)  BF1(6,msk)  BF1(7,msk) \
    BF1(8,msk)  BF1(9,msk)  BF1(10,msk) BF1(11,msk) \
    BF1(12,msk) BF1(13,msk) BF1(14,msk) BF1(15,msk)

__global__ __launch_bounds__(256, 2) void vq_kernel(const float* __restrict__ x,
                                                    const char* __restrict__ wsb,
                                                    int* __restrict__ out) {
    __shared__ __align__(16) f4 xs4[ROWSB][17];   // x staging (only LDS user)
    __shared__ float sEn[1024];

    const int tid = threadIdx.x;
    const int lane = tid & 63;
    const int w = __builtin_amdgcn_readfirstlane(tid >> 6);   // wave id 0..3
    const int l31 = lane & 31;
    const int lh = lane >> 5;             // 0/1: k-half + C/D row offset
    const int lh8 = lh * 8;
    const int w32 = w * 32;
    const int lane16 = lane * 16;
    const int n0 = blockIdx.x * ROWSB;
    const int b = n0 >> 12;
    const int hw0 = n0 & (HW - 1);

    // stage e-norms
    const float* enp = (const float*)(wsb + 384 * 1024);
#pragma unroll
    for (int q = 0; q < 4; ++q) sEn[q * 256 + tid] = enp[q * 256 + tid];

    // stage x tile (fp32): wave w loads channels w*16..w*16+15 of all 128 rows
    {
        const float* g = x + ((size_t)b * D_DIM + w * 16) * HW + hw0 + lane;
        float v[16], v2[16];
#pragma unroll
        for (int i = 0; i < 16; ++i) { v[i] = g[(size_t)i * HW]; v2[i] = g[(size_t)i * HW + 64]; }
#pragma unroll
        for (int j = 0; j < 4; ++j) {
            xs4[lane][w * 4 + j]      = (f4){v[4*j],  v[4*j+1],  v[4*j+2],  v[4*j+3]};
            xs4[lane + 64][w * 4 + j] = (f4){v2[4*j], v2[4*j+1], v2[4*j+2], v2[4*j+3]};
        }
    }
    __syncthreads();

    // build A frags of (-2x) for THIS wave's 32 rows: 4 ksteps x 3 levels
    s8v Ah0, Am0, Al0, Ah1, Am1, Al1, Ah2, Am2, Al2, Ah3, Am3, Al3;
    BUILD_A(0) BUILD_A(1) BUILD_A(2) BUILD_A(3)

    float best0=INF_, best1=INF_, best2=INF_, best3=INF_;
    float best4=INF_, best5=INF_, best6=INF_, best7=INF_;
    float best8=INF_, best9=INF_, best10=INF_, best11=INF_;
    float best12=INF_, best13=INF_, best14=INF_, best15=INF_;
    int idx0=0, idx1=0, idx2=0, idx3=0, idx4=0, idx5=0, idx6=0, idx7=0;
    int idx8=0, idx9=0, idx10=0, idx11=0, idx12=0, idx13=0, idx14=0, idx15=0;

    // pipeline state: distances + code-base of the previous tile
    f32x16 svp;
#pragma unroll
    for (int i = 0; i < 16; ++i) svp[i] = INF_;   // first-tile UPDs are no-ops
    int kprev = 0;

    // seed acc chains for tile 0
    f32x16 c0, c1 = Z16;
    {
        const float en0 = sEn[l31];
#pragma unroll
        for (int i = 0; i < 16; ++i) c0[i] = en0;
    }

    // B-fragment register double-buffer sets (12 s8v each)
    s8v BA0h, BA0m, BA0l, BA1h, BA1m, BA1l, BA2h, BA2m, BA2l, BA3h, BA3m, BA3l;
    s8v BB0h, BB0m, BB0l, BB1h, BB1m, BB1l, BB2h, BB2m, BB2l, BB3h, BB3m, BB3l;

    LDG(A, wsb)                  // tile 0 into set A

#pragma unroll 1
    for (int t = 0; t < 16; ++t) {
        const int tA = 2 * t;                      // tile in set A
        // prefetch tile tA+1 into set B, then MFMA tile tA from set A
        LDG(B, wsb + (size_t)(tA + 1) * 12288)
        K24(A)
        // prefetch tile tA+2 into set A (t=15: wraps to 0, discarded)
        LDG(A, wsb + (size_t)((tA + 2) & 31) * 12288)
        UPD_ALL                                    // argmin of tile tA-1
        FINISH(tA * 32, tA + 1)
        // MFMA tile tA+1 from set B
        K24(B)
        UPD_ALL                                    // argmin of tile tA
        FINISH((tA + 1) * 32, tA + 2)
    }

    // drain the pipeline: argmin of tile 31
    UPD_ALL

    // per-row argmin across the 32 cols held by this lane's 32-lane half
    BFALL(1) BFALL(2) BFALL(4) BFALL(8) BFALL(16)

    // lane l31==0 of each half holds 16 rows of this wave's 32-row stripe:
    // reg i -> row (i&3) + 8*(i>>2) + 4*lh.  4x int4 stores.
    if (l31 == 0) {
        int* op = out + n0 + w32 + lh * 4;
        int4 q0; q0.x = idx0;  q0.y = idx1;  q0.z = idx2;  q0.w = idx3;
        int4 q1; q1.x = idx4;  q1.y = idx5;  q1.z = idx6;  q1.w = idx7;
        int4 q2; q2.x = idx8;  q2.y = idx9;  q2.z = idx10; q2.w = idx11;
        int4 q3; q3.x = idx12; q3.y = idx13; q3.z = idx14; q3.w = idx15;
        *(int4*)(op)      = q0;
        *(int4*)(op + 8)  = q1;
        *(int4*)(op + 16) = q2;
        *(int4*)(op + 24) = q3;
    }
}

extern "C" void kernel_launch(void* const* d_in, const int* in_sizes, int n_in,
                              void* d_out, int out_size, void* d_ws, size_t ws_size,
                              hipStream_t stream) {
    const float* x  = (const float*)d_in[0];   // [16,64,64,64] fp32
    const float* cb = (const float*)d_in[1];   // [1024,64] fp32
    char* wsb = (char*)d_ws;                   // 384KB packed cb + 4KB enorm
    int*  out = (int*)d_out;                   // 65536 int32 indices

    prep_kernel<<<dim3(400), dim3(64), 0, stream>>>(cb, wsb);
    vq_kernel<<<dim3(65536 / ROWSB), dim3(256), 0, stream>>>(x, wsb, out);
}

// Round 8
// 109.874 us; speedup vs baseline: 1.0742x; 1.0742x over previous
//
#include <hip/hip_runtime.h>

// VQ argmin via MFMA: x [16,64,64,64] NCHW fp32, codebook [1024,64] fp32.
// dist = ||e||^2 + (-2x).e  (||x||^2 dropped).  -2x.e computed as bf16 3-way
// split GEMM (h/m/l, keep level-sum<=2 products: hh,hm,mh,hl,mm,lh) -> exact
// to ~2^-26, below fp32 rounding noise.
//
// R16: R8-R15 (7 schedules) all serialize LDS/MFMA/VALU per wave.  Mechanism:
// CDNA waves issue IN ORDER -- an MFMA stalled on the busy matrix pipe blocks
// everything behind it.  All prior rounds emitted MFMAs as one dense cluster
// with VALU/LDS segregated outside, wrapped in setprio + asm fences (compiler
// scheduling barriers), and in R9/R11 the argmin depended on the current
// accs.  So nothing could interleave; pipes ran serially by construction.
// R16 = R11 (best, 55.9us) with the pins removed:
//  - ping-pong acc sets P/Q: phase P computes into one, argmin of P-1 reads
//    the other (no dep on current MFMAs)
//  - accs seeded with ||e||^2 (uniform over the lane's 4 C-regs) -> +en gone
//  - NO setprio, NO fences around MFMAs; only the R11 protocol waits
//    (vmcnt(3)+lgkmcnt(0) before one raw barrier/phase, proven race-free)
//  - B-reads split into two 6-read half-tiles so tile1 reads interleave into
//    tile0's MFMA shadow
// Compiler is now free to slot the 32 UPD ops + 12 ds_reads + 3 gl_lds into
// the ~460-cyc MFMA issue shadow of each phase.

typedef float f4 __attribute__((ext_vector_type(4)));
typedef short s8v __attribute__((ext_vector_type(8)));
typedef unsigned int u32;

#define D_DIM 64
#define HW    4096
#define ROWS  64
#define INF_  __builtin_inff()
#define MFMA16(a,b,c) __builtin_amdgcn_mfma_f32_16x16x32_bf16(a,b,c,0,0,0)
#define Z4 (f4){0.f,0.f,0.f,0.f}

__device__ __forceinline__ unsigned short bf_rne(float f) {
    u32 u = __builtin_bit_cast(u32, f);
    u32 r = u + 0x7fffu + ((u >> 16) & 1u);
    return (unsigned short)(r >> 16);
}
__device__ __forceinline__ float bf_to_f(unsigned short h) {
    u32 u = ((u32)h) << 16;
    return __builtin_bit_cast(float, u);
}
__device__ __forceinline__ void split3(float f, unsigned short& h,
                                       unsigned short& m, unsigned short& l) {
    h = bf_rne(f);
    float f1 = f - bf_to_f(h);
    m = bf_rne(f1);
    float f2 = f1 - bf_to_f(m);
    l = bf_rne(f2);
}
__device__ __forceinline__ s8v pack8(unsigned short a0, unsigned short a1,
                                     unsigned short a2, unsigned short a3,
                                     unsigned short a4, unsigned short a5,
                                     unsigned short a6, unsigned short a7) {
    uint4 u;
    u.x = a0 | ((u32)a1 << 16);
    u.y = a2 | ((u32)a3 << 16);
    u.z = a4 | ((u32)a5 << 16);
    u.w = a6 | ((u32)a7 << 16);
    return __builtin_bit_cast(s8v, u);
}

// ---- prep: split codebook into B-fragment-ordered bf16 h/m/l chunks + enorm.
// Chunk c = T*6 + s*3 + L (T = 16-code tile 0..63, s = kstep, L = level):
// 64 lanes x 16B.  lane: code = T*16 + (lane&15), ch = s*32 + (lane>>4)*8 + j
// (B[k][n]: n = lane&15, k = (lane>>4)*8+j).  enorm (fp32) at ws + 384KB.
__global__ __launch_bounds__(64) void prep_kernel(const float* __restrict__ cb,
                                                  char* __restrict__ wsb) {
    const int blk = blockIdx.x;
    const int lane = threadIdx.x;
    if (blk < 384) {
        const int T = blk / 6;
        const int rem = blk - T * 6;
        const int s = rem / 3;
        const int L = rem - s * 3;
        const int code = T * 16 + (lane & 15);
        const int ch0 = s * 32 + (lane >> 4) * 8;
        const float* src = cb + code * 64 + ch0;
        unsigned short o[8];
#pragma unroll
        for (int j = 0; j < 8; ++j) {
            unsigned short h, m2, l;
            split3(src[j], h, m2, l);
            o[j] = (L == 0) ? h : (L == 1) ? m2 : l;
        }
        uint4 w;
        w.x = o[0] | ((u32)o[1] << 16);
        w.y = o[2] | ((u32)o[3] << 16);
        w.z = o[4] | ((u32)o[5] << 16);
        w.w = o[6] | ((u32)o[7] << 16);
        *(uint4*)(wsb + (size_t)blk * 1024 + lane * 16) = w;
    } else {
        const int k = (blk - 384) * 64 + lane;
        const f4* row = (const f4*)(cb + (size_t)k * 64);
        float sacc = 0.f;
#pragma unroll
        for (int i = 0; i < 16; ++i) {
            f4 v = row[i];
            sacc = fmaf(v.x, v.x, sacc);
            sacc = fmaf(v.y, v.y, sacc);
            sacc = fmaf(v.z, v.z, sacc);
            sacc = fmaf(v.w, v.w, sacc);
        }
        ((float*)(wsb + 384 * 1024))[k] = sacc;
    }
}

// async global->LDS, 16B per lane: LDS dest = wave-uniform base (HW adds
// lane*16); global src is per-lane (carries the lane*16 term).
__device__ __forceinline__ void gl_lds16(const char* g, char* l) {
    __builtin_amdgcn_global_load_lds(
        (const __attribute__((address_space(1))) void*)g,
        (__attribute__((address_space(3))) void*)l, 16, 0, 0);
}

// build A-frags of (-2x) for this wave's 16 rows, kstep s
#define BUILD_A(s) { \
    const float* xr = (const float*)&xs4[w16 + m_][0]; \
    f4 va = *(const f4*)(xr + (s) * 32 + ko); \
    f4 vb = *(const f4*)(xr + (s) * 32 + ko + 4); \
    unsigned short h0,h1,h2,h3,h4,h5,h6,h7; \
    unsigned short q0,q1,q2,q3,q4,q5,q6,q7; \
    unsigned short l0,l1,l2,l3,l4,l5,l6,l7; \
    split3(-2.f * va.x, h0, q0, l0); split3(-2.f * va.y, h1, q1, l1); \
    split3(-2.f * va.z, h2, q2, l2); split3(-2.f * va.w, h3, q3, l3); \
    split3(-2.f * vb.x, h4, q4, l4); split3(-2.f * vb.y, h5, q5, l5); \
    split3(-2.f * vb.z, h6, q6, l6); split3(-2.f * vb.w, h7, q7, l7); \
    Ah##s = pack8(h0,h1,h2,h3,h4,h5,h6,h7); \
    Am##s = pack8(q0,q1,q2,q3,q4,q5,q6,q7); \
    Al##s = pack8(l0,l1,l2,l3,l4,l5,l6,l7); \
}

// argmin update of one acc pair (tile t of set S), code KN — independent of
// the CURRENT phase's MFMAs (reads the other ping-pong set).
#define U1(S, t, i, KN) { \
    float v = S##t##a[i] + S##t##b[i]; \
    bool pr = (v < best##i); \
    best##i = pr ? v : best##i; \
    idx##i  = pr ? (KN) : idx##i; \
}
#define UPDS(S, kn) \
    U1(S,0,0,kn)      U1(S,0,1,kn)      U1(S,0,2,kn)      U1(S,0,3,kn) \
    U1(S,1,0,(kn)+16) U1(S,1,1,(kn)+16) U1(S,1,2,(kn)+16) U1(S,1,3,(kn)+16)

// one phase (32 codes): stage tile P+2; read+MFMA two 16-code half-tiles into
// set PS; argmin-update previous phase from set QS; protocol waits; barrier;
// rotate.  No setprio, no fences around the MFMAs.
#define PH(PS, QS) { \
    gl_lds16(gp + stageoff,        b2 + wu); \
    gl_lds16(gp + stageoff + 1024, b2 + wu + 1024); \
    gl_lds16(gp + stageoff + 2048, b2 + wu + 2048); \
    const char* bb = b0 + lane16; \
    const float en0 = sEn[p32 + m_]; \
    const float en1 = sEn[p32 + 16 + m_]; \
    PS##0a = (f4){en0,en0,en0,en0}; PS##0b = Z4; \
    PS##1a = (f4){en1,en1,en1,en1}; PS##1b = Z4; \
    s8v Bh0 = *(const s8v*)(bb); \
    s8v Bm0 = *(const s8v*)(bb + 1024); \
    s8v Bl0 = *(const s8v*)(bb + 2048); \
    s8v Bh1 = *(const s8v*)(bb + 3072); \
    s8v Bm1 = *(const s8v*)(bb + 4096); \
    s8v Bl1 = *(const s8v*)(bb + 5120); \
    PS##0a = MFMA16(Ah0,Bh0,PS##0a); PS##0b = MFMA16(Ah1,Bh1,PS##0b); \
    PS##0a = MFMA16(Ah0,Bm0,PS##0a); PS##0b = MFMA16(Ah1,Bm1,PS##0b); \
    PS##0a = MFMA16(Am0,Bh0,PS##0a); PS##0b = MFMA16(Am1,Bh1,PS##0b); \
    PS##0a = MFMA16(Ah0,Bl0,PS##0a); PS##0b = MFMA16(Ah1,Bl1,PS##0b); \
    PS##0a = MFMA16(Am0,Bm0,PS##0a); PS##0b = MFMA16(Am1,Bm1,PS##0b); \
    PS##0a = MFMA16(Al0,Bh0,PS##0a); PS##0b = MFMA16(Al1,Bh1,PS##0b); \
    s8v Ch0 = *(const s8v*)(bb + 6144); \
    s8v Cm0 = *(const s8v*)(bb + 7168); \
    s8v Cl0 = *(const s8v*)(bb + 8192); \
    s8v Ch1 = *(const s8v*)(bb + 9216); \
    s8v Cm1 = *(const s8v*)(bb + 10240); \
    s8v Cl1 = *(const s8v*)(bb + 11264); \
    PS##1a = MFMA16(Ah0,Ch0,PS##1a); PS##1b = MFMA16(Ah1,Ch1,PS##1b); \
    PS##1a = MFMA16(Ah0,Cm0,PS##1a); PS##1b = MFMA16(Ah1,Cm1,PS##1b); \
    PS##1a = MFMA16(Am0,Ch0,PS##1a); PS##1b = MFMA16(Am1,Ch1,PS##1b); \
    PS##1a = MFMA16(Ah0,Cl0,PS##1a); PS##1b = MFMA16(Ah1,Cl1,PS##1b); \
    PS##1a = MFMA16(Am0,Cm0,PS##1a); PS##1b = MFMA16(Am1,Cm1,PS##1b); \
    PS##1a = MFMA16(Al0,Ch0,PS##1a); PS##1b = MFMA16(Al1,Ch1,PS##1b); \
    { const int kn = p32 - 32 + m_; UPDS(QS, kn) } \
    asm volatile("s_waitcnt vmcnt(3) lgkmcnt(0)" ::: "memory"); \
    __builtin_amdgcn_s_barrier(); \
    { char* t = b0; b0 = b1; b1 = b2; b2 = t; } \
    gp += 12288; \
    if (gp == gend) gp = wsb; \
    p32 += 32; \
}

#define BF1(i, msk) { \
    float ov = __shfl_xor(best##i, msk); \
    int   oi = __shfl_xor(idx##i,  msk); \
    bool pr = (ov < best##i) || (ov == best##i && oi < idx##i); \
    best##i = pr ? ov : best##i; \
    idx##i  = pr ? oi : idx##i; \
}
#define BFALL(msk) BF1(0,msk) BF1(1,msk) BF1(2,msk) BF1(3,msk)

__global__ __launch_bounds__(256, 4) void vq_kernel(const float* __restrict__ x,
                                                    const char* __restrict__ wsb,
                                                    int* __restrict__ out) {
    // union: xs4[64][17] f4 (17408B) lives here until A-build done, then the
    // same region becomes the 3x12288B B staging buffers.
    __shared__ __align__(16) char smem[36864];
    __shared__ float sEn[1024];
    f4 (*xs4)[17] = (f4 (*)[17])smem;
    char* const sB = smem;

    const int tid = threadIdx.x;
    const int lane = tid & 63;
    const int w = __builtin_amdgcn_readfirstlane(tid >> 6);   // wave id 0..3
    const int m_ = lane & 15;
    const int ko = (lane >> 4) * 8;
    const int w16 = w * 16;
    const int wu = w * 3072;              // wave-uniform LDS stage offset
    const int lane16 = lane * 16;
    const int stageoff = wu + lane16;     // per-lane global stage offset
    const int n0 = blockIdx.x * ROWS;
    const int b = n0 >> 12;
    const int hw0 = n0 & (HW - 1);

    // stage e-norms
    const float* enp = (const float*)(wsb + 384 * 1024);
#pragma unroll
    for (int q = 0; q < 4; ++q) sEn[q * 256 + tid] = enp[q * 256 + tid];

    // stage x tile (fp32): wave w loads channels w*16..w*16+15 of all 64 rows
    {
        const float* g = x + ((size_t)b * D_DIM + w16) * HW + hw0 + lane;
        float v[16];
#pragma unroll
        for (int i = 0; i < 16; ++i) v[i] = g[(size_t)i * HW];
#pragma unroll
        for (int j = 0; j < 4; ++j)
            xs4[lane][w * 4 + j] = (f4){v[4*j], v[4*j+1], v[4*j+2], v[4*j+3]};
    }
    __syncthreads();

    // build A frags of (-2x) for THIS wave's 16 rows: 2 ksteps x 3 levels
    s8v Ah0, Am0, Al0, Ah1, Am1, Al1;
    BUILD_A(0) BUILD_A(1)
    __syncthreads();          // all waves done with xs4 -> smem becomes sB

    // 3 rotating staging buffers (12KB = one 32-code phase), prefetch dist 2
    char* b0 = sB;                 // holds phase P   (read this phase)
    char* b1 = sB + 12288;         // holds phase P+1 (in flight / landed)
    char* b2 = sB + 24576;         // write target: phase P+2

    // prologue: issue phases 0 and 1 (6 loads outstanding per wave)
    gl_lds16(wsb + stageoff,                b0 + wu);
    gl_lds16(wsb + stageoff + 1024,         b0 + wu + 1024);
    gl_lds16(wsb + stageoff + 2048,         b0 + wu + 2048);
    gl_lds16(wsb + 12288 + stageoff,        b1 + wu);
    gl_lds16(wsb + 12288 + stageoff + 1024, b1 + wu + 1024);
    gl_lds16(wsb + 12288 + stageoff + 2048, b1 + wu + 2048);

    float best0 = INF_, best1 = INF_, best2 = INF_, best3 = INF_;
    int idx0 = 0, idx1 = 0, idx2 = 0, idx3 = 0;

    // ping-pong accumulator sets; Q starts INF so phase-(-1) UPDs are no-ops
    f4 p0a, p0b, p1a, p1b;
    f4 q0a = (f4){INF_,INF_,INF_,INF_}, q0b = Z4;
    f4 q1a = (f4){INF_,INF_,INF_,INF_}, q1b = Z4;

    // own phase-0 loads landed (phase-1's 3 stay in flight), THEN barrier:
    // after it, phase 0's tile is landed for ALL waves.
    asm volatile("s_waitcnt vmcnt(3)" ::: "memory");
    __builtin_amdgcn_s_barrier();

    const char* gp = wsb + 2 * 12288;           // global src for phase P+2
    const char* const gend = wsb + 32 * 12288;
    int p32 = 0;

#pragma unroll 1
    for (int pp = 0; pp < 16; ++pp) {
        PH(p, q)      // even phase: compute set P, argmin prev from set Q
        PH(q, p)      // odd phase:  compute set Q, argmin prev from set P
    }
    asm volatile("s_waitcnt vmcnt(0)" ::: "memory");   // drain before exit

    // drain the pipeline: argmin of the final phase (set Q, p32 == 1024)
    { const int kn = p32 - 32 + m_; UPDS(q, kn) }

    // per-row argmin across the 16 code-classes in each 16-lane group
    BFALL(1) BFALL(2) BFALL(4) BFALL(8)

    // lane m_==0 of each group holds rows (lane>>4)*4 .. +3 of this wave's
    // 16-row stripe; write 4 contiguous indices as int4
    if (m_ == 0) {
        int4 o4; o4.x = idx0; o4.y = idx1; o4.z = idx2; o4.w = idx3;
        *(int4*)(out + n0 + w16 + (lane >> 4) * 4) = o4;
    }
}

extern "C" void kernel_launch(void* const* d_in, const int* in_sizes, int n_in,
                              void* d_out, int out_size, void* d_ws, size_t ws_size,
                              hipStream_t stream) {
    const float* x  = (const float*)d_in[0];   // [16,64,64,64] fp32
    const float* cb = (const float*)d_in[1];   // [1024,64] fp32
    char* wsb = (char*)d_ws;                   // 384KB packed cb + 4KB enorm
    int*  out = (int*)d_out;                   // 65536 int32 indices

    prep_kernel<<<dim3(400), dim3(64), 0, stream>>>(cb, wsb);
    vq_kernel<<<dim3(65536 / ROWS), dim3(256), 0, stream>>>(x, wsb, out);
}